// Round 8
// baseline (21.351 us; speedup 1.0000x reference)
//
#include <hip/hip_runtime.h>
#include <hip/hip_bf16.h>

typedef __bf16 bf16x8 __attribute__((ext_vector_type(8)));
typedef float f32x4 __attribute__((ext_vector_type(4)));

#define K_DIM 1024
#define N_DIM 128

// ws layout:
//   [0, 1MB)   Tfrag: [rg:256][ks:4][lane:64][elem:8] bf16
//
// Fragment convention (validated R0-R7, mfma_f32_16x16x32_bf16):
//   operand: 16-idx = lane%16, k = 4*(lane/16) + (e&3) + 16*(e>>2)
//   D: col = lane&15 (= operand2's 16-idx), row = 4*(lane>>4)+i (= operand1's)
//
// Structure lessons:
//   R4/R5: in-dispatch cross-block deps (grid.sync / flag spin) cost 14-55us.
//   R6: per-block B re-read from f32 is ~3.8us serial L2 time -> prep stays
//       a separate tiny dispatch.
//   R3 vs R7: body changes moved total by <0.5us -> ~13us is launch/graph
//       fixed overhead; remaining levers are in-body waste only.

__device__ inline unsigned pk2(float x, float y) {
  __hip_bfloat16 hx = __float2bfloat16(x), hy = __float2bfloat16(y);
  return (unsigned)*(unsigned short*)&hx | ((unsigned)*(unsigned short*)&hy << 16);
}

// ---------------------------------------------------------------------------
// prep: B (1024x128 f32) -> Bfrag. 256 blocks x 64 thr (1 wave each, one
// load->convert->store round trip). Wave W = (w=W>>5, ks=W&31).
// ---------------------------------------------------------------------------
__global__ __launch_bounds__(64)
void prep_kernel(const float* __restrict__ B, unsigned short* __restrict__ Bfrag) {
  const int W = blockIdx.x, l = threadIdx.x;
  const int w = W >> 5, ks = W & 31;
  const int col = 16 * w + (l & 15);
  const int kb = 32 * ks + 4 * (l >> 4);
  unsigned u[4];
#pragma unroll
  for (int j = 0; j < 4; ++j) {
    int k0 = kb + 2 * (j & 1) + 16 * (j >> 1);
    u[j] = pk2(B[(size_t)k0 * N_DIM + col], B[(size_t)(k0 + 1) * N_DIM + col]);
  }
  *(uint4*)&Bfrag[((size_t)(w * 32 + ks) * 64 + l) * 8] =
      make_uint4(u[0], u[1], u[2], u[3]);
}

// ---------------------------------------------------------------------------
// K1: T = batch @ B. 256 blocks x 512 thr (8 waves, 1 block/CU).
// A-stage: each thread builds ONE full 16B fragment (two f32x4 loads, 4 pk2)
// and writes uint4 to LDS at consecutive-lane addresses -> conflict-free
// (fixes the 196608 SQ_LDS_BANK_CONFLICT of the 8B-scatter version).
// B fragments prefetched upfront into registers (32 coalesced dwordx4).
// k-loop: ds_read_b128 + MFMA only. Epilogue: single 8B Tfrag store.
// ---------------------------------------------------------------------------
__global__ __launch_bounds__(512, 2)
void proj_kernel(const float* __restrict__ batch,
                 const unsigned short* __restrict__ Bfrag,
                 unsigned short* __restrict__ Tfrag) {
  __shared__ __align__(16) unsigned short Asl[32 * 64 * 8];  // 32 KB
  const int t = threadIdx.x, w = t >> 6, l = t & 63;
  const int blk = blockIdx.x;
  const int m0 = blk * 16;

  // ---- stage A: thread t round j owns fragment f = j*512+t ----
  // frag (ks = f>>6, lane = f&63): row r = lane&15, quad g = lane>>4,
  // elems = A[r][32ks+4g+{0..3}] , A[r][32ks+16+4g+{0..3}]
  {
    const float* src = batch + (size_t)m0 * K_DIM;
#pragma unroll
    for (int j = 0; j < 4; ++j) {
      int f = j * 512 + t;
      int ks = f >> 6, lane = f & 63;
      int r = lane & 15, g = lane >> 4;
      const float* p = src + (size_t)r * K_DIM + 32 * ks + 4 * g;
      f32x4 g0 = *(const f32x4*)p;
      f32x4 g1 = *(const f32x4*)(p + 16);
      uint4 u = make_uint4(pk2(g0.x, g0.y), pk2(g0.z, g0.w),
                           pk2(g1.x, g1.y), pk2(g1.z, g1.w));
      int byte = ks * 1024 + ((lane * 16) ^ ((ks & 7) << 4));
      *(uint4*)((char*)Asl + byte) = u;
    }
  }

  // ---- prefetch B fragments into registers (coalesced dwordx4, L2-hit) ----
  bf16x8 bfr[32];
  {
    const unsigned short* bptr = Bfrag + ((size_t)w * 32 * 64 + l) * 8;
#pragma unroll
    for (int ks = 0; ks < 32; ++ks)
      bfr[ks] = *(const bf16x8*)(bptr + (size_t)ks * 512);
  }
  __syncthreads();

  // ---- k-loop: pure LDS + MFMA, zero barriers ----
  f32x4 acc0 = {0.f, 0.f, 0.f, 0.f}, acc1 = {0.f, 0.f, 0.f, 0.f};
#pragma unroll
  for (int ks = 0; ks < 32; ks += 2) {
    bf16x8 a0 = *(const bf16x8*)((const char*)Asl +
                   (ks * 1024 + ((l * 16) ^ ((ks & 7) << 4))));
    acc0 = __builtin_amdgcn_mfma_f32_16x16x32_bf16(bfr[ks], a0, acc0, 0, 0, 0);
    bf16x8 a1 = *(const bf16x8*)((const char*)Asl +
                   ((ks + 1) * 1024 + ((l * 16) ^ (((ks + 1) & 7) << 4))));
    acc1 = __builtin_amdgcn_mfma_f32_16x16x32_bf16(bfr[ks + 1], a1, acc1, 0, 0, 0);
  }
  f32x4 acc = acc0 + acc1;

  // ---- store T fragment (validated layout); norms now computed in dist ----
  *(uint2*)&Tfrag[(((size_t)blk * 4 + (w >> 1)) * 64 + l) * 8 + (w & 1) * 4] =
      make_uint2(pk2(acc[0], acc[1]), pk2(acc[2], acc[3]));
}

// ---------------------------------------------------------------------------
// K2: out[b,i,j] = n_i + n_j - 2*(T_i.T_j). 1024 blocks x 256 thr
// (4096 waves, 4 blocks/CU). Wave = 16x16 tile: 8 frag loads, 4 MFMA.
// Norms computed IN-REGISTER from the fragments (each wave's ifr/jfr span
// the full K for its 16 rows/cols): nj is lane-local, ni needs 4 permutes.
// ---------------------------------------------------------------------------
__global__ __launch_bounds__(256)
void dist_kernel(const unsigned short* __restrict__ Tfrag,
                 float* __restrict__ out) {
  const int t = threadIdx.x, l = t & 63;
  const int W = blockIdx.x * 4 + (t >> 6);  // 0..4095
  const int bb = W >> 8, tile = W & 255;
  const int ti = (tile >> 4) * 16, tj = (tile & 15) * 16;
  const int rbase = bb * 256;

  bf16x8 ifr[4], jfr[4];
#pragma unroll
  for (int ks = 0; ks < 4; ++ks) {
    ifr[ks] = *(const bf16x8*)
        &Tfrag[((((size_t)bb * 16 + (ti >> 4)) * 4 + ks) * 64 + l) * 8];
    jfr[ks] = *(const bf16x8*)
        &Tfrag[((((size_t)bb * 16 + (tj >> 4)) * 4 + ks) * 64 + l) * 8];
  }

  f32x4 acc = {0.f, 0.f, 0.f, 0.f};
#pragma unroll
  for (int ks = 0; ks < 4; ++ks)
    acc = __builtin_amdgcn_mfma_f32_16x16x32_bf16(ifr[ks], jfr[ks], acc, 0, 0, 0);

  // ---- in-register norms ----
  // lane l holds k-slices of row i = ti+(l&15) (ifr) and col j = tj+(l&15)
  // (jfr); xor-reduce over the 4 lane-quads completes the K sum.
  float si = 0.f, sj = 0.f;
#pragma unroll
  for (int ks = 0; ks < 4; ++ks)
#pragma unroll
    for (int e = 0; e < 8; ++e) {
      float vi = (float)ifr[ks][e];
      float vj = (float)jfr[ks][e];
      si += vi * vi;
      sj += vj * vj;
    }
  si += __shfl_xor(si, 16); si += __shfl_xor(si, 32);
  sj += __shfl_xor(sj, 16); sj += __shfl_xor(sj, 32);
  // now: si = ||T[ti+(l&15)]||^2, sj = ||T[tj+(l&15)]||^2

#pragma unroll
  for (int ii = 0; ii < 4; ++ii) {
    int row = 4 * (l >> 4) + ii;            // D-layout row for this lane
    float ni = __shfl(si, row);             // from lane holding that row
    out[(size_t)(rbase + ti + row) * 256 + tj + (l & 15)] =
        ni + sj - 2.f * acc[ii];
  }
}

extern "C" void kernel_launch(void* const* d_in, const int* in_sizes, int n_in,
                              void* d_out, int out_size, void* d_ws, size_t ws_size,
                              hipStream_t stream) {
  const float* batch = (const float*)d_in[0];  // (16,256,1024) f32
  const float* Bmat  = (const float*)d_in[1];  // (1024,128) f32
  unsigned short* Tfrag = (unsigned short*)d_ws;              // 1 MB
  unsigned short* Bfrag = Tfrag + 256 * 4 * 64 * 8;           // 256 KB
  float* out = (float*)d_out;                                 // (16,256,256) f32

  prep_kernel<<<256, 64, 0, stream>>>(Bmat, Bfrag);
  proj_kernel<<<256, 512, 0, stream>>>(batch, Bfrag, Tfrag);
  dist_kernel<<<1024, 256, 0, stream>>>(Tfrag, out);
}